// Round 17
// baseline (196.288 us; speedup 1.0000x reference)
//
#include <hip/hip_runtime.h>

#define NN 100000
#define NE 2400000
#define NB 391              // buckets of 256 dst nodes
#define CAPB 6912           // binned per-bucket capacity (mean 6144, +9.8 sigma)
#define CAPC 7296           // csr per-bucket capacity (padded lists, mean ~6528)
#define EPB 4096            // edges per sort block
#define NBLK2 ((NE + EPB - 1) / EPB)   // 586

__device__ __forceinline__ int wexscan(int v, int lane) {
    int x = v;
#pragma unroll
    for (int off = 1; off < 64; off <<= 1) {
        int t = __shfl_up(x, off, 64);
        x += (lane >= off) ? t : 0;
    }
    return x - v;            // exclusive prefix within wave64
}

// ---------------- pass 1: per-block bucket histogram (no global atomics) ----------------
__global__ __launch_bounds__(512) void k_hist(const int* __restrict__ ei,
        int* __restrict__ bh) {
    __shared__ int hist[NB];
    int tid = threadIdx.x;
    for (int i = tid; i < NB; i += 512) hist[i] = 0;
    __syncthreads();
    int base_e = blockIdx.x * EPB + tid * 8;
    if (base_e + 8 <= NE) {                  // NE%8==0: all-or-nothing per thread
        int4 da = *(const int4*)(ei + NE + base_e);
        int4 db = *(const int4*)(ei + NE + base_e + 4);
        atomicAdd(&hist[da.x >> 8], 1); atomicAdd(&hist[da.y >> 8], 1);
        atomicAdd(&hist[da.z >> 8], 1); atomicAdd(&hist[da.w >> 8], 1);
        atomicAdd(&hist[db.x >> 8], 1); atomicAdd(&hist[db.y >> 8], 1);
        atomicAdd(&hist[db.z >> 8], 1); atomicAdd(&hist[db.w >> 8], 1);
    }
    __syncthreads();
    for (int i = tid; i < NB; i += 512) bh[blockIdx.x * NB + i] = hist[i];
}

// ---------------- pass 2: per-bucket scan over blocks -> exact offsets ----------------
__global__ __launch_bounds__(256) void k_offscan(int* __restrict__ bh,
        int* __restrict__ tot) {
    __shared__ int wsum[4];
    int b = blockIdx.x, tid = threadIdx.x;
    int lane = tid & 63, wid = tid >> 6;
    int carry = 0;
#pragma unroll
    for (int r = 0; r < 3; ++r) {            // ceil(586/256)=3 rounds
        int blk = r * 256 + tid;
        int v = (blk < NBLK2) ? bh[blk * NB + b] : 0;
        int ex = wexscan(v, lane);
        if (lane == 63) wsum[wid] = ex + v;
        __syncthreads();
        int woff = 0, rt = 0;
#pragma unroll
        for (int i = 0; i < 4; ++i) {
            woff += (i < wid) ? wsum[i] : 0;
            rt += wsum[i];
        }
        if (blk < NBLK2) bh[blk * NB + b] = b * CAPB + carry + woff + ex;
        carry += rt;
        __syncthreads();
    }
    if (tid == 0) tot[b] = carry;
}

// ---------------- pass 3: scatter to bucket regions (no global atomics) ----------------
__global__ __launch_bounds__(512) void k_scatter2(const int* __restrict__ ei,
        const int* __restrict__ bh, int* __restrict__ binned) {
    __shared__ int hist[NB], lbase[NB], myb[NB];
    __shared__ int stage[EPB];
    __shared__ unsigned short stageb[EPB];
    __shared__ int wsum[8];
    int tid = threadIdx.x;
    for (int i = tid; i < NB; i += 512) {
        hist[i] = 0;
        myb[i] = bh[blockIdx.x * NB + i];    // precomputed exact base
    }
    __syncthreads();
    int base_e = blockIdx.x * EPB + tid * 8;
    int pk[8], bn[8], rk[8];
    if (base_e + 8 <= NE) {
        const int4* s4 = (const int4*)(ei + base_e);
        const int4* d4 = (const int4*)(ei + NE + base_e);
        int4 sa = s4[0], sb = s4[1], da = d4[0], db = d4[1];
        int ss[8] = {sa.x, sa.y, sa.z, sa.w, sb.x, sb.y, sb.z, sb.w};
        int dd[8] = {da.x, da.y, da.z, da.w, db.x, db.y, db.z, db.w};
#pragma unroll
        for (int k = 0; k < 8; ++k) {
            bn[k] = dd[k] >> 8;
            pk[k] = ss[k] | ((dd[k] & 255) << 17);
            rk[k] = atomicAdd(&hist[bn[k]], 1);      // LDS rank only
        }
    } else {
#pragma unroll
        for (int k = 0; k < 8; ++k) bn[k] = -1;
    }
    __syncthreads();
    int lane = tid & 63, wid = tid >> 6;
    int v = (tid < NB) ? hist[tid] : 0;
    int ex = wexscan(v, lane);
    if (lane == 63) wsum[wid] = ex + v;
    __syncthreads();
    int woff = 0, tot = 0;
#pragma unroll
    for (int i = 0; i < 8; ++i) {
        int s = wsum[i];
        woff += (i < wid) ? s : 0;
        tot += s;
    }
    ex += woff;
    if (tid < NB) lbase[tid] = ex;
    __syncthreads();
#pragma unroll
    for (int k = 0; k < 8; ++k) {
        if (bn[k] >= 0) {
            int slot = lbase[bn[k]] + rk[k];
            stage[slot] = pk[k];
            stageb[slot] = (unsigned short)bn[k];
        }
    }
    __syncthreads();
    for (int j = tid; j < tot; j += 512) {
        int b = stageb[j];
        binned[myb[b] + (j - lbase[b])] = stage[j];
    }
}

// ---------------- per-bucket degree count -> rsp (padded starts), dinv, xs ----------------
__global__ __launch_bounds__(256) void k_csr_count(const int* __restrict__ binned,
        const int* __restrict__ tot, const float* __restrict__ x,
        int* __restrict__ rsp, float* __restrict__ dinv, float2* __restrict__ xs) {
    __shared__ int cnt[256];
    __shared__ int wsum[4];
    int tid = threadIdx.x, b = blockIdx.x;
    int base = b * CAPB, n = tot[b];
    cnt[tid] = 0;
    __syncthreads();
    int n4 = n >> 2;
    const int4* b4 = (const int4*)(binned + base);
    for (int j = tid; j < n4; j += 256) {
        int4 w = b4[j];
        atomicAdd(&cnt[(w.x >> 17) & 255], 1);
        atomicAdd(&cnt[(w.y >> 17) & 255], 1);
        atomicAdd(&cnt[(w.z >> 17) & 255], 1);
        atomicAdd(&cnt[(w.w >> 17) & 255], 1);
    }
    for (int j = (n4 << 2) + tid; j < n; j += 256)
        atomicAdd(&cnt[(binned[base + j] >> 17) & 255], 1);
    __syncthreads();
    int deg = cnt[tid];
    int pdeg = (deg + 3) & ~3;               // padded list length (mult of 4)
    int lane = tid & 63, wid = tid >> 6;
    int ex = wexscan(pdeg, lane);
    if (lane == 63) wsum[wid] = ex + pdeg;
    __syncthreads();
    int woff = 0;
#pragma unroll
    for (int i = 0; i < 4; ++i) woff += (i < wid) ? wsum[i] : 0;
    ex += woff;
    int node = (b << 8) + tid;
    if (node < NN) {
        rsp[node] = ((b * CAPC + ex) << 8) | deg;        // padded start | true deg
        float di = rsqrtf((float)(deg + 1));             // +1 self-loop
        dinv[node] = di;
        float2 xv = ((const float2*)x)[node];
        xs[node] = make_float2(di * xv.x, di * xv.y);
    }
    if (b == 0 && tid == 0) xs[NN] = make_float2(0.f, 0.f);   // sentinel
}

// ---------------- csr placement (+pads), then per-node int4 walk -> At ----------------
// xs fully written by k_csr_count (previous launch) -> safe to read any node here.
__global__ __launch_bounds__(256) void k_csr_place(const int* __restrict__ binned,
        const int* __restrict__ tot, const int* __restrict__ rsp,
        const float2* __restrict__ xs, const float* __restrict__ dinv,
        int* __restrict__ csr, float4* __restrict__ At, float* __restrict__ h3) {
    __shared__ int cur2[256];
    int tid = threadIdx.x, b = blockIdx.x;
    int base = b * CAPB, n = tot[b];
    int cbase = b * CAPC;
    int node = (b << 8) + tid;
    int rp = (node < NN) ? rsp[node] : 0;
    int nstart = (rp >> 8) - cbase;           // in-bucket padded start
    int deg = rp & 255;
    cur2[tid] = (node < NN) ? nstart : 0;
    __syncthreads();
    int n4 = n >> 2;
    const int4* b4 = (const int4*)(binned + base);
    for (int j = tid; j < n4; j += 256) {
        int4 w = b4[j];
        int p0 = atomicAdd(&cur2[(w.x >> 17) & 255], 1); csr[cbase + p0] = w.x & 0x1FFFF;
        int p1 = atomicAdd(&cur2[(w.y >> 17) & 255], 1); csr[cbase + p1] = w.y & 0x1FFFF;
        int p2 = atomicAdd(&cur2[(w.z >> 17) & 255], 1); csr[cbase + p2] = w.z & 0x1FFFF;
        int p3 = atomicAdd(&cur2[(w.w >> 17) & 255], 1); csr[cbase + p3] = w.w & 0x1FFFF;
    }
    for (int j = (n4 << 2) + tid; j < n; j += 256) {
        int w = binned[base + j];
        int p = atomicAdd(&cur2[(w >> 17) & 255], 1);
        csr[cbase + p] = w & 0x1FFFF;
    }
    // fill own node's pad slots with sentinel NN
    if (node < NN) {
        int pdeg = (deg + 3) & ~3;
        for (int p = nstart + deg; p < nstart + pdeg; ++p) csr[cbase + p] = NN;
    }
    if (b == 0 && tid == 0) {                 // sentinels for fly / gather_out
        At[NN] = make_float4(0.f, 0.f, 0.f, 0.f);
        h3[NN] = 0.f;
    }
    __syncthreads();                          // csr slice complete (in-block, L2-hot)
    if (node < NN) {
        int beg = rp >> 8;
        int pdeg = (deg + 3) & ~3;
        float ax = 0.f, ay = 0.f;
        const int4* c4 = (const int4*)(csr + beg);       // 16B-aligned
        for (int j = 0; j < (pdeg >> 2); ++j) {
            int4 s = c4[j];
            float2 v0 = xs[s.x], v1 = xs[s.y], v2 = xs[s.z], v3 = xs[s.w];
            ax += (v0.x + v1.x) + (v2.x + v3.x);         // pads -> xs[NN]=0
            ay += (v0.y + v1.y) + (v2.y + v3.y);
        }
        float di = dinv[node];
        float2 xn = xs[node];                 // self-loop term
        At[node] = make_float4(di * (ax + xn.x), di * (ay + xn.y), di, 0.f);
    }
}

// ---------------- layer-2 gather: LDS-broadcast h1 recompute, padded lists ----------------
__global__ __launch_bounds__(256) void k_gather_fly(const float4* __restrict__ At,
        const int* __restrict__ rsp, const int* __restrict__ csr,
        const float* __restrict__ W1, const float* __restrict__ b1,
        const float* __restrict__ W2, const float* __restrict__ b2,
        const float* __restrict__ W3, float* __restrict__ h3) {
    __shared__ float WsT[32 * 36];            // transposed W2, row stride 36 (16B-aligned)
    __shared__ float accS[256];
    __shared__ float4 stage[8][32];
    int tid = threadIdx.x;
    for (int j = tid; j < 1024; j += 256) {
        int k = j >> 5, fo = j & 31;
        WsT[fo * 36 + k] = W2[j];             // WsT[f][k] = W2[k][f]
    }
    __syncthreads();                          // early: all waves arrive together
    int g = tid >> 5, f = tid & 31;
    int node = blockIdx.x * 8 + g;                         // grid*8 == NN exactly
    float w0f = W1[f], w1f = W1[32 + f], bf = b1[f];
    float4 an = At[node];
    int r = rsp[node];
    float di = an.z;
    float vs = fmaf(an.y, w1f, fmaf(an.x, w0f, bf));
    float acc0 = di * fmaxf(vs, 0.f), acc1 = 0.f;          // self-loop
    int beg = r >> 8, deg = r & 255;
    int pdeg = (deg + 3) & ~3;                // padded length (pads -> At[NN]=0)
    float4* st = &stage[g][0];
    int b0 = 0;
    for (; b0 + 32 <= pdeg; b0 += 32) {       // full chunks: branch-free loads
        float4 a = At[csr[beg + b0 + f]];
        st[f] = a;
        __asm__ __volatile__("" ::: "memory");             // DS pipe is in-order
#pragma unroll
        for (int j = 0; j < 32; j += 2) {
            float4 e0 = st[j], e1 = st[j + 1];             // same-addr broadcast reads
            float v0 = fmaf(e0.y, w1f, fmaf(e0.x, w0f, bf));
            acc0 = fmaf(e0.z, fmaxf(v0, 0.f), acc0);
            float v1 = fmaf(e1.y, w1f, fmaf(e1.x, w0f, bf));
            acc1 = fmaf(e1.z, fmaxf(v1, 0.f), acc1);
        }
        __asm__ __volatile__("" ::: "memory");
    }
    int rem = pdeg - b0;                      // multiple of 4, < 32
    if (rem > 0) {
        float4 a = make_float4(0.f, 0.f, 0.f, 0.f);
        if (f < rem) a = At[csr[beg + b0 + f]];            // pads valid via sentinel
        st[f] = a;
        __asm__ __volatile__("" ::: "memory");
        for (int j = 0; j < rem; j += 4) {    // only rem iterations, 4-unrolled
            float4 e0 = st[j], e1 = st[j + 1], e2 = st[j + 2], e3 = st[j + 3];
            float v0 = fmaf(e0.y, w1f, fmaf(e0.x, w0f, bf));
            acc0 = fmaf(e0.z, fmaxf(v0, 0.f), acc0);
            float v1 = fmaf(e1.y, w1f, fmaf(e1.x, w0f, bf));
            acc1 = fmaf(e1.z, fmaxf(v1, 0.f), acc1);
            float v2 = fmaf(e2.y, w1f, fmaf(e2.x, w0f, bf));
            acc0 = fmaf(e2.z, fmaxf(v2, 0.f), acc0);
            float v3 = fmaf(e3.y, w1f, fmaf(e3.x, w0f, bf));
            acc1 = fmaf(e3.z, fmaxf(v3, 0.f), acc1);
        }
        __asm__ __volatile__("" ::: "memory");
    }
    accS[tid] = di * (acc0 + acc1);           // agg2 = di * (sum + self); intra-wave only
    __asm__ __volatile__("" ::: "memory");
    int n0 = tid & 224;                       // group base (same wave)
    float sum = b2[f];
    const float* wrow = &WsT[f * 36];
#pragma unroll
    for (int k = 0; k < 32; k += 4) {
        float4 a4 = *(const float4*)&accS[n0 + k];   // group-broadcast, aligned
        float4 w4 = *(const float4*)&wrow[k];        // lane-private row, aligned
        sum = fmaf(a4.x, w4.x, sum);
        sum = fmaf(a4.y, w4.y, sum);
        sum = fmaf(a4.z, w4.z, sum);
        sum = fmaf(a4.w, w4.w, sum);
    }
    float h2 = fmaxf(sum, 0.f);
    float v = di * h2 * W3[f];
#pragma unroll
    for (int off = 16; off > 0; off >>= 1) v += __shfl_down(v, off, 32);
    if (f == 0) h3[node] = v;
}

// ---------------- width-1 gather -> out (int4 walk) ----------------
__global__ __launch_bounds__(256) void k_gather_out(const float* __restrict__ hs,
        const int* __restrict__ rsp, const int* __restrict__ csr,
        const float* __restrict__ dinv, const float* __restrict__ bias,
        float* __restrict__ out) {
    int node = blockIdx.x * 256 + threadIdx.x;
    if (node >= NN) return;
    int r = rsp[node];
    int beg = r >> 8, deg = r & 255;
    int pdeg = (deg + 3) & ~3;
    float acc = hs[node];
    const int4* c4 = (const int4*)(csr + beg);           // 16B-aligned
    for (int j = 0; j < (pdeg >> 2); ++j) {
        int4 s = c4[j];
        acc += (hs[s.x] + hs[s.y]) + (hs[s.z] + hs[s.w]); // pads -> hs[NN]=0
    }
    out[node] = dinv[node] * acc + bias[0];
}

extern "C" void kernel_launch(void* const* d_in, const int* in_sizes, int n_in,
                              void* d_out, int out_size, void* d_ws, size_t ws_size,
                              hipStream_t stream) {
    const float* x  = (const float*)d_in[0];
    const int*   ei = (const int*)d_in[1];   // [2, NE] int32
    const float* W1 = (const float*)d_in[2];
    const float* b1 = (const float*)d_in[3];
    const float* W2 = (const float*)d_in[4];
    const float* b2 = (const float*)d_in[5];
    const float* W3 = (const float*)d_in[6];
    const float* b3 = (const float*)d_in[7];
    float* out = (float*)d_out;

    char* w = (char*)d_ws;
    float4* At    = (float4*)w; w += (NN + 1) * 16;     // +1 sentinel, 16B-aligned first
    float2* xs    = (float2*)w; w += (NN + 1) * 8;
    int*   bh     = (int*)w;    w += NBLK2 * NB * 4;    // 0.9 MB block-hist/offsets
    int*   tot    = (int*)w;    w += NB * 4;
    int*   rsp    = (int*)w;    w += NN * 4;
    float* dinv   = (float*)w;  w += NN * 4;
    int*   binned = (int*)w;    w += NB * CAPB * 4;     // 10.8 MB
    int*   csr    = (int*)w;    w += NB * CAPC * 4;     // 11.4 MB
    float* h3     = (float*)w;  w += (NN + 1) * 4;

    const int G_N = (NN + 255) / 256;        // 391
    const int G_G = NN / 8;                  // 12500 (exact)

    k_hist<<<NBLK2, 512, 0, stream>>>(ei, bh);
    k_offscan<<<NB, 256, 0, stream>>>(bh, tot);
    k_scatter2<<<NBLK2, 512, 0, stream>>>(ei, bh, binned);
    k_csr_count<<<NB, 256, 0, stream>>>(binned, tot, x, rsp, dinv, xs);
    k_csr_place<<<NB, 256, 0, stream>>>(binned, tot, rsp, xs, dinv, csr, At, h3);
    k_gather_fly<<<G_G, 256, 0, stream>>>(At, rsp, csr, W1, b1, W2, b2, W3, h3);
    k_gather_out<<<G_N, 256, 0, stream>>>(h3, rsp, csr, dinv, b3, out);
}

// Round 18
// 192.481 us; speedup vs baseline: 1.0198x; 1.0198x over previous
//
#include <hip/hip_runtime.h>

#define NN 100000
#define NE 2400000
#define NB 391              // buckets of 256 dst nodes
#define CAP 6912            // per-bucket edge capacity (mean 6144, +9.8 sigma)
#define EPB 4096            // edges per sort block
#define NBLK2 ((NE + EPB - 1) / EPB)   // 586

__device__ __forceinline__ int wexscan(int v, int lane) {
    int x = v;
#pragma unroll
    for (int off = 1; off < 64; off <<= 1) {
        int t = __shfl_up(x, off, 64);
        x += (lane >= off) ? t : 0;
    }
    return x - v;            // exclusive prefix within wave64
}

// ---------------- pass 1: per-block bucket histogram (no global atomics) ----------------
__global__ __launch_bounds__(512) void k_hist(const int* __restrict__ ei,
        int* __restrict__ bh) {
    __shared__ int hist[NB];
    int tid = threadIdx.x;
    for (int i = tid; i < NB; i += 512) hist[i] = 0;
    __syncthreads();
    int base_e = blockIdx.x * EPB + tid * 8;
    if (base_e + 8 <= NE) {                  // NE%8==0: all-or-nothing per thread
        int4 da = *(const int4*)(ei + NE + base_e);
        int4 db = *(const int4*)(ei + NE + base_e + 4);
        atomicAdd(&hist[da.x >> 8], 1); atomicAdd(&hist[da.y >> 8], 1);
        atomicAdd(&hist[da.z >> 8], 1); atomicAdd(&hist[da.w >> 8], 1);
        atomicAdd(&hist[db.x >> 8], 1); atomicAdd(&hist[db.y >> 8], 1);
        atomicAdd(&hist[db.z >> 8], 1); atomicAdd(&hist[db.w >> 8], 1);
    }
    __syncthreads();
    for (int i = tid; i < NB; i += 512) bh[blockIdx.x * NB + i] = hist[i];
}

// ---------------- pass 2: per-bucket scan over blocks -> exact offsets ----------------
__global__ __launch_bounds__(256) void k_offscan(int* __restrict__ bh,
        int* __restrict__ tot) {
    __shared__ int wsum[4];
    int b = blockIdx.x, tid = threadIdx.x;
    int lane = tid & 63, wid = tid >> 6;
    int carry = 0;
#pragma unroll
    for (int r = 0; r < 3; ++r) {            // ceil(586/256)=3 rounds
        int blk = r * 256 + tid;
        int v = (blk < NBLK2) ? bh[blk * NB + b] : 0;
        int ex = wexscan(v, lane);
        if (lane == 63) wsum[wid] = ex + v;
        __syncthreads();
        int woff = 0, rt = 0;
#pragma unroll
        for (int i = 0; i < 4; ++i) {
            woff += (i < wid) ? wsum[i] : 0;
            rt += wsum[i];
        }
        if (blk < NBLK2) bh[blk * NB + b] = b * CAP + carry + woff + ex;
        carry += rt;
        __syncthreads();
    }
    if (tid == 0) tot[b] = carry;
}

// ---------------- pass 3: scatter to bucket regions (no global atomics) ----------------
__global__ __launch_bounds__(512) void k_scatter2(const int* __restrict__ ei,
        const int* __restrict__ bh, int* __restrict__ binned) {
    __shared__ int hist[NB], lbase[NB], myb[NB];
    __shared__ int stage[EPB];
    __shared__ unsigned short stageb[EPB];
    __shared__ int wsum[8];
    int tid = threadIdx.x;
    for (int i = tid; i < NB; i += 512) {
        hist[i] = 0;
        myb[i] = bh[blockIdx.x * NB + i];    // precomputed exact base
    }
    __syncthreads();
    int base_e = blockIdx.x * EPB + tid * 8;
    int pk[8], bn[8], rk[8];
    if (base_e + 8 <= NE) {
        const int4* s4 = (const int4*)(ei + base_e);
        const int4* d4 = (const int4*)(ei + NE + base_e);
        int4 sa = s4[0], sb = s4[1], da = d4[0], db = d4[1];
        int ss[8] = {sa.x, sa.y, sa.z, sa.w, sb.x, sb.y, sb.z, sb.w};
        int dd[8] = {da.x, da.y, da.z, da.w, db.x, db.y, db.z, db.w};
#pragma unroll
        for (int k = 0; k < 8; ++k) {
            bn[k] = dd[k] >> 8;
            pk[k] = ss[k] | ((dd[k] & 255) << 17);
            rk[k] = atomicAdd(&hist[bn[k]], 1);      // LDS rank only
        }
    } else {
#pragma unroll
        for (int k = 0; k < 8; ++k) bn[k] = -1;
    }
    __syncthreads();
    int lane = tid & 63, wid = tid >> 6;
    int v = (tid < NB) ? hist[tid] : 0;
    int ex = wexscan(v, lane);
    if (lane == 63) wsum[wid] = ex + v;
    __syncthreads();
    int woff = 0, tot = 0;
#pragma unroll
    for (int i = 0; i < 8; ++i) {
        int s = wsum[i];
        woff += (i < wid) ? s : 0;
        tot += s;
    }
    ex += woff;
    if (tid < NB) lbase[tid] = ex;
    __syncthreads();
#pragma unroll
    for (int k = 0; k < 8; ++k) {
        if (bn[k] >= 0) {
            int slot = lbase[bn[k]] + rk[k];
            stage[slot] = pk[k];
            stageb[slot] = (unsigned short)bn[k];
        }
    }
    __syncthreads();
    for (int j = tid; j < tot; j += 512) {
        int b = stageb[j];
        binned[myb[b] + (j - lbase[b])] = stage[j];
    }
}

// ---------------- per-bucket degree count -> rsp, dinv, prescaled xs ----------------
__global__ __launch_bounds__(256) void k_csr_count(const int* __restrict__ binned,
        const int* __restrict__ tot, const float* __restrict__ x,
        int* __restrict__ rsp, float* __restrict__ dinv, float2* __restrict__ xs) {
    __shared__ int cnt[256];
    __shared__ int wsum[4];
    int tid = threadIdx.x, b = blockIdx.x;
    int base = b * CAP, n = tot[b];
    cnt[tid] = 0;
    __syncthreads();
    int n4 = n >> 2;
    const int4* b4 = (const int4*)(binned + base);
    for (int j = tid; j < n4; j += 256) {
        int4 w = b4[j];
        atomicAdd(&cnt[(w.x >> 17) & 255], 1);
        atomicAdd(&cnt[(w.y >> 17) & 255], 1);
        atomicAdd(&cnt[(w.z >> 17) & 255], 1);
        atomicAdd(&cnt[(w.w >> 17) & 255], 1);
    }
    for (int j = (n4 << 2) + tid; j < n; j += 256)
        atomicAdd(&cnt[(binned[base + j] >> 17) & 255], 1);
    __syncthreads();
    int deg = cnt[tid];
    int lane = tid & 63, wid = tid >> 6;
    int ex = wexscan(deg, lane);
    if (lane == 63) wsum[wid] = ex + deg;
    __syncthreads();
    int woff = 0;
#pragma unroll
    for (int i = 0; i < 4; ++i) woff += (i < wid) ? wsum[i] : 0;
    ex += woff;
    int node = (b << 8) + tid;
    if (node < NN) {
        rsp[node] = ((base + ex) << 8) | deg;            // packed start|deg
        float di = rsqrtf((float)(deg + 1));             // +1 self-loop
        dinv[node] = di;
        float2 xv = ((const float2*)x)[node];
        xs[node] = make_float2(di * xv.x, di * xv.y);
    }
}

// ---------------- csr placement, then per-node register walk -> At ----------------
// xs fully written by k_csr_count (previous launch) -> safe to read any node here.
__global__ __launch_bounds__(256) void k_csr_place(const int* __restrict__ binned,
        const int* __restrict__ tot, const int* __restrict__ rsp,
        const float2* __restrict__ xs, const float* __restrict__ dinv,
        int* __restrict__ csr, float4* __restrict__ At) {
    __shared__ int cur2[256];
    int tid = threadIdx.x, b = blockIdx.x;
    int base = b * CAP, n = tot[b];
    int node = (b << 8) + tid;
    int rp = (node < NN) ? rsp[node] : 0;
    cur2[tid] = (node < NN) ? ((rp >> 8) - base) : 0;
    __syncthreads();
    int n4 = n >> 2;
    const int4* b4 = (const int4*)(binned + base);
    for (int j = tid; j < n4; j += 256) {
        int4 w = b4[j];
        int p0 = atomicAdd(&cur2[(w.x >> 17) & 255], 1); csr[base + p0] = w.x & 0x1FFFF;
        int p1 = atomicAdd(&cur2[(w.y >> 17) & 255], 1); csr[base + p1] = w.y & 0x1FFFF;
        int p2 = atomicAdd(&cur2[(w.z >> 17) & 255], 1); csr[base + p2] = w.z & 0x1FFFF;
        int p3 = atomicAdd(&cur2[(w.w >> 17) & 255], 1); csr[base + p3] = w.w & 0x1FFFF;
    }
    for (int j = (n4 << 2) + tid; j < n; j += 256) {
        int w = binned[base + j];
        int p = atomicAdd(&cur2[(w >> 17) & 255], 1);
        csr[base + p] = w & 0x1FFFF;
    }
    __syncthreads();                          // csr slice complete (in-block, L2-hot)
    if (node < NN) {
        int beg = rp >> 8, deg = rp & 255;
        float ax = 0.f, ay = 0.f;
        int e = beg, end = beg + deg;
        for (; e + 4 <= end; e += 4) {
            int s0 = csr[e], s1 = csr[e + 1], s2 = csr[e + 2], s3 = csr[e + 3];
            float2 v0 = xs[s0], v1 = xs[s1], v2 = xs[s2], v3 = xs[s3];
            ax += (v0.x + v1.x) + (v2.x + v3.x);
            ay += (v0.y + v1.y) + (v2.y + v3.y);
        }
        for (; e < end; ++e) { float2 vv = xs[csr[e]]; ax += vv.x; ay += vv.y; }
        float di = dinv[node];
        float2 xn = xs[node];                 // self-loop term
        At[node] = make_float4(di * (ax + xn.x), di * (ay + xn.y), di, 0.f);
    }
}

// ---------------- layer-2 gather: LDS-broadcast h1 recompute + W2/W3 epilogue ----------------
__global__ __launch_bounds__(256) void k_gather_fly(const float4* __restrict__ At,
        const int* __restrict__ rsp, const int* __restrict__ csr,
        const float* __restrict__ W1, const float* __restrict__ b1,
        const float* __restrict__ W2, const float* __restrict__ b2,
        const float* __restrict__ W3, float* __restrict__ h3) {
    __shared__ float WsT[32 * 36];            // transposed W2, row stride 36 (16B-aligned)
    __shared__ float accS[256];
    __shared__ float4 stage[8][32];
    int tid = threadIdx.x;
    for (int j = tid; j < 1024; j += 256) {
        int k = j >> 5, fo = j & 31;
        WsT[fo * 36 + k] = W2[j];             // WsT[f][k] = W2[k][f]
    }
    __syncthreads();                          // early: all waves arrive together
    int g = tid >> 5, f = tid & 31;
    int node = blockIdx.x * 8 + g;                         // grid*8 == NN exactly
    float w0f = W1[f], w1f = W1[32 + f], bf = b1[f];
    float4 an = At[node];
    int r = rsp[node];
    float di = an.z;
    float vs = fmaf(an.y, w1f, fmaf(an.x, w0f, bf));
    float acc0 = di * fmaxf(vs, 0.f), acc1 = 0.f;          // self-loop
    int beg = r >> 8, deg = r & 255;
    float4* st = &stage[g][0];
    for (int b0 = 0; b0 < (deg & ~31); b0 += 32) {         // full 32-chunks
        float4 a = At[csr[beg + b0 + f]];
        st[f] = a;                                         // in-wave exchange,
        __asm__ __volatile__("" ::: "memory");             // DS pipe is in-order
#pragma unroll
        for (int j = 0; j < 32; j += 2) {
            float4 e0 = st[j], e1 = st[j + 1];             // same-addr broadcast reads
            float v0 = fmaf(e0.y, w1f, fmaf(e0.x, w0f, bf));
            acc0 = fmaf(e0.z, fmaxf(v0, 0.f), acc0);
            float v1 = fmaf(e1.y, w1f, fmaf(e1.x, w0f, bf));
            acc1 = fmaf(e1.z, fmaxf(v1, 0.f), acc1);
        }
        __asm__ __volatile__("" ::: "memory");
    }
    int rem = deg & 31;
    if (rem > 0) {
        int b0 = deg & ~31;
        float4 a = make_float4(0.f, 0.f, 0.f, 0.f);        // az=0 pads contribute 0
        if (f < rem) a = At[csr[beg + b0 + f]];
        st[f] = a;                                         // all 32 slots written
        __asm__ __volatile__("" ::: "memory");
        int rem2 = (rem + 1) & ~1;            // dynamic bound: skip zero-pad iterations
        for (int j = 0; j < rem2; j += 2) {
            float4 e0 = st[j], e1 = st[j + 1];
            float v0 = fmaf(e0.y, w1f, fmaf(e0.x, w0f, bf));
            acc0 = fmaf(e0.z, fmaxf(v0, 0.f), acc0);
            float v1 = fmaf(e1.y, w1f, fmaf(e1.x, w0f, bf));
            acc1 = fmaf(e1.z, fmaxf(v1, 0.f), acc1);
        }
        __asm__ __volatile__("" ::: "memory");
    }
    accS[tid] = di * (acc0 + acc1);           // agg2 = di * (sum + self); intra-wave only
    __asm__ __volatile__("" ::: "memory");
    int n0 = tid & 224;                       // group base (same wave)
    float sum = b2[f];
    const float* wrow = &WsT[f * 36];
#pragma unroll
    for (int k = 0; k < 32; k += 4) {
        float4 a4 = *(const float4*)&accS[n0 + k];   // group-broadcast, aligned
        float4 w4 = *(const float4*)&wrow[k];        // lane-private row, aligned
        sum = fmaf(a4.x, w4.x, sum);
        sum = fmaf(a4.y, w4.y, sum);
        sum = fmaf(a4.z, w4.z, sum);
        sum = fmaf(a4.w, w4.w, sum);
    }
    float h2 = fmaxf(sum, 0.f);
    float v = di * h2 * W3[f];
#pragma unroll
    for (int off = 16; off > 0; off >>= 1) v += __shfl_down(v, off, 32);
    if (f == 0) h3[node] = v;
}

// ---------------- width-1 gather -> out ----------------
__global__ __launch_bounds__(256) void k_gather_out(const float* __restrict__ hs,
        const int* __restrict__ rsp, const int* __restrict__ csr,
        const float* __restrict__ dinv, const float* __restrict__ bias,
        float* __restrict__ out) {
    int node = blockIdx.x * 256 + threadIdx.x;
    if (node >= NN) return;
    int r = rsp[node];
    int beg = r >> 8, end = beg + (r & 255);
    float acc = hs[node];
    int e = beg;
    for (; e + 4 <= end; e += 4) {
        int s0 = csr[e], s1 = csr[e + 1], s2 = csr[e + 2], s3 = csr[e + 3];
        acc += (hs[s0] + hs[s1]) + (hs[s2] + hs[s3]);
    }
    for (; e < end; ++e) acc += hs[csr[e]];
    out[node] = dinv[node] * acc + bias[0];
}

extern "C" void kernel_launch(void* const* d_in, const int* in_sizes, int n_in,
                              void* d_out, int out_size, void* d_ws, size_t ws_size,
                              hipStream_t stream) {
    const float* x  = (const float*)d_in[0];
    const int*   ei = (const int*)d_in[1];   // [2, NE] int32
    const float* W1 = (const float*)d_in[2];
    const float* b1 = (const float*)d_in[3];
    const float* W2 = (const float*)d_in[4];
    const float* b2 = (const float*)d_in[5];
    const float* W3 = (const float*)d_in[6];
    const float* b3 = (const float*)d_in[7];
    float* out = (float*)d_out;

    char* w = (char*)d_ws;
    float4* At    = (float4*)w; w += NN * 16;           // 16B-aligned first, 1.6 MB
    float2* xs    = (float2*)w; w += NN * 8;
    int*   bh     = (int*)w;    w += NBLK2 * NB * 4;    // 0.9 MB block-hist/offsets
    int*   tot    = (int*)w;    w += NB * 4;
    int*   rsp    = (int*)w;    w += NN * 4;
    float* dinv   = (float*)w;  w += NN * 4;
    int*   binned = (int*)w;    w += NB * CAP * 4;      // 10.8 MB
    int*   csr    = (int*)w;    w += NB * CAP * 4;      // 10.8 MB
    float* h3     = (float*)w;  w += NN * 4;

    const int G_N = (NN + 255) / 256;        // 391
    const int G_G = NN / 8;                  // 12500 (exact)

    k_hist<<<NBLK2, 512, 0, stream>>>(ei, bh);
    k_offscan<<<NB, 256, 0, stream>>>(bh, tot);
    k_scatter2<<<NBLK2, 512, 0, stream>>>(ei, bh, binned);
    k_csr_count<<<NB, 256, 0, stream>>>(binned, tot, x, rsp, dinv, xs);
    k_csr_place<<<NB, 256, 0, stream>>>(binned, tot, rsp, xs, dinv, csr, At);
    k_gather_fly<<<G_G, 256, 0, stream>>>(At, rsp, csr, W1, b1, W2, b2, W3, h3);
    k_gather_out<<<G_N, 256, 0, stream>>>(h3, rsp, csr, dinv, b3, out);
}

// Round 19
// 187.018 us; speedup vs baseline: 1.0496x; 1.0292x over previous
//
#include <hip/hip_runtime.h>

#define NN 100000
#define NE 2400000
#define NB 391              // buckets of 256 dst nodes
#define CAP 6912            // per-bucket edge capacity (mean 6144, +9.8 sigma)
#define EPB 4096            // edges per sort block
#define NBLK2 ((NE + EPB - 1) / EPB)   // 586

__device__ __forceinline__ int wexscan(int v, int lane) {
    int x = v;
#pragma unroll
    for (int off = 1; off < 64; off <<= 1) {
        int t = __shfl_up(x, off, 64);
        x += (lane >= off) ? t : 0;
    }
    return x - v;            // exclusive prefix within wave64
}

// ---------------- pass 1: per-block bucket histogram (no global atomics) ----------------
__global__ __launch_bounds__(512) void k_hist(const int* __restrict__ ei,
        int* __restrict__ bh) {
    __shared__ int hist[NB];
    int tid = threadIdx.x;
    for (int i = tid; i < NB; i += 512) hist[i] = 0;
    __syncthreads();
    int base_e = blockIdx.x * EPB + tid * 8;
    if (base_e + 8 <= NE) {                  // NE%8==0: all-or-nothing per thread
        int4 da = *(const int4*)(ei + NE + base_e);
        int4 db = *(const int4*)(ei + NE + base_e + 4);
        atomicAdd(&hist[da.x >> 8], 1); atomicAdd(&hist[da.y >> 8], 1);
        atomicAdd(&hist[da.z >> 8], 1); atomicAdd(&hist[da.w >> 8], 1);
        atomicAdd(&hist[db.x >> 8], 1); atomicAdd(&hist[db.y >> 8], 1);
        atomicAdd(&hist[db.z >> 8], 1); atomicAdd(&hist[db.w >> 8], 1);
    }
    __syncthreads();
    for (int i = tid; i < NB; i += 512) bh[blockIdx.x * NB + i] = hist[i];
}

// ---------------- pass 2: per-bucket scan over blocks -> exact offsets ----------------
__global__ __launch_bounds__(256) void k_offscan(int* __restrict__ bh,
        int* __restrict__ tot) {
    __shared__ int wsum[4];
    int b = blockIdx.x, tid = threadIdx.x;
    int lane = tid & 63, wid = tid >> 6;
    int carry = 0;
#pragma unroll
    for (int r = 0; r < 3; ++r) {            // ceil(586/256)=3 rounds
        int blk = r * 256 + tid;
        int v = (blk < NBLK2) ? bh[blk * NB + b] : 0;
        int ex = wexscan(v, lane);
        if (lane == 63) wsum[wid] = ex + v;
        __syncthreads();
        int woff = 0, rt = 0;
#pragma unroll
        for (int i = 0; i < 4; ++i) {
            woff += (i < wid) ? wsum[i] : 0;
            rt += wsum[i];
        }
        if (blk < NBLK2) bh[blk * NB + b] = b * CAP + carry + woff + ex;
        carry += rt;
        __syncthreads();
    }
    if (tid == 0) tot[b] = carry;
}

// ---------------- pass 3: scatter to bucket regions (no global atomics) ----------------
__global__ __launch_bounds__(512) void k_scatter2(const int* __restrict__ ei,
        const int* __restrict__ bh, int* __restrict__ binned) {
    __shared__ int hist[NB], lbase[NB], myb[NB];
    __shared__ int stage[EPB];
    __shared__ unsigned short stageb[EPB];
    __shared__ int wsum[8];
    int tid = threadIdx.x;
    for (int i = tid; i < NB; i += 512) {
        hist[i] = 0;
        myb[i] = bh[blockIdx.x * NB + i];    // precomputed exact base
    }
    __syncthreads();
    int base_e = blockIdx.x * EPB + tid * 8;
    int pk[8], bn[8], rk[8];
    if (base_e + 8 <= NE) {
        const int4* s4 = (const int4*)(ei + base_e);
        const int4* d4 = (const int4*)(ei + NE + base_e);
        int4 sa = s4[0], sb = s4[1], da = d4[0], db = d4[1];
        int ss[8] = {sa.x, sa.y, sa.z, sa.w, sb.x, sb.y, sb.z, sb.w};
        int dd[8] = {da.x, da.y, da.z, da.w, db.x, db.y, db.z, db.w};
#pragma unroll
        for (int k = 0; k < 8; ++k) {
            bn[k] = dd[k] >> 8;
            pk[k] = ss[k] | ((dd[k] & 255) << 17);
            rk[k] = atomicAdd(&hist[bn[k]], 1);      // LDS rank only
        }
    } else {
#pragma unroll
        for (int k = 0; k < 8; ++k) bn[k] = -1;
    }
    __syncthreads();
    int lane = tid & 63, wid = tid >> 6;
    int v = (tid < NB) ? hist[tid] : 0;
    int ex = wexscan(v, lane);
    if (lane == 63) wsum[wid] = ex + v;
    __syncthreads();
    int woff = 0, tot = 0;
#pragma unroll
    for (int i = 0; i < 8; ++i) {
        int s = wsum[i];
        woff += (i < wid) ? s : 0;
        tot += s;
    }
    ex += woff;
    if (tid < NB) lbase[tid] = ex;
    __syncthreads();
#pragma unroll
    for (int k = 0; k < 8; ++k) {
        if (bn[k] >= 0) {
            int slot = lbase[bn[k]] + rk[k];
            stage[slot] = pk[k];
            stageb[slot] = (unsigned short)bn[k];
        }
    }
    __syncthreads();
    for (int j = tid; j < tot; j += 512) {
        int b = stageb[j];
        binned[myb[b] + (j - lbase[b])] = stage[j];
    }
}

// ---------------- per-bucket degree count -> rsp, dinv, prescaled xs ----------------
__global__ __launch_bounds__(256) void k_csr_count(const int* __restrict__ binned,
        const int* __restrict__ tot, const float* __restrict__ x,
        int* __restrict__ rsp, float* __restrict__ dinv, float2* __restrict__ xs) {
    __shared__ int cnt[256];
    __shared__ int wsum[4];
    int tid = threadIdx.x, b = blockIdx.x;
    int base = b * CAP, n = tot[b];
    cnt[tid] = 0;
    __syncthreads();
    int n4 = n >> 2;
    const int4* b4 = (const int4*)(binned + base);
    for (int j = tid; j < n4; j += 256) {
        int4 w = b4[j];
        atomicAdd(&cnt[(w.x >> 17) & 255], 1);
        atomicAdd(&cnt[(w.y >> 17) & 255], 1);
        atomicAdd(&cnt[(w.z >> 17) & 255], 1);
        atomicAdd(&cnt[(w.w >> 17) & 255], 1);
    }
    for (int j = (n4 << 2) + tid; j < n; j += 256)
        atomicAdd(&cnt[(binned[base + j] >> 17) & 255], 1);
    __syncthreads();
    int deg = cnt[tid];
    int lane = tid & 63, wid = tid >> 6;
    int ex = wexscan(deg, lane);
    if (lane == 63) wsum[wid] = ex + deg;
    __syncthreads();
    int woff = 0;
#pragma unroll
    for (int i = 0; i < 4; ++i) woff += (i < wid) ? wsum[i] : 0;
    ex += woff;
    int node = (b << 8) + tid;
    if (node < NN) {
        rsp[node] = ((base + ex) << 8) | deg;            // packed start|deg
        float di = rsqrtf((float)(deg + 1));             // +1 self-loop
        dinv[node] = di;
        float2 xv = ((const float2*)x)[node];
        xs[node] = make_float2(di * xv.x, di * xv.y);
    }
}

// ---------------- csr placement, then per-node register walk -> At ----------------
// xs fully written by k_csr_count (previous launch) -> safe to read any node here.
__global__ __launch_bounds__(256) void k_csr_place(const int* __restrict__ binned,
        const int* __restrict__ tot, const int* __restrict__ rsp,
        const float2* __restrict__ xs, const float* __restrict__ dinv,
        int* __restrict__ csr, float4* __restrict__ At) {
    __shared__ int cur2[256];
    int tid = threadIdx.x, b = blockIdx.x;
    int base = b * CAP, n = tot[b];
    int node = (b << 8) + tid;
    int rp = (node < NN) ? rsp[node] : 0;
    cur2[tid] = (node < NN) ? ((rp >> 8) - base) : 0;
    __syncthreads();
    int n4 = n >> 2;
    const int4* b4 = (const int4*)(binned + base);
    for (int j = tid; j < n4; j += 256) {
        int4 w = b4[j];
        int p0 = atomicAdd(&cur2[(w.x >> 17) & 255], 1); csr[base + p0] = w.x & 0x1FFFF;
        int p1 = atomicAdd(&cur2[(w.y >> 17) & 255], 1); csr[base + p1] = w.y & 0x1FFFF;
        int p2 = atomicAdd(&cur2[(w.z >> 17) & 255], 1); csr[base + p2] = w.z & 0x1FFFF;
        int p3 = atomicAdd(&cur2[(w.w >> 17) & 255], 1); csr[base + p3] = w.w & 0x1FFFF;
    }
    for (int j = (n4 << 2) + tid; j < n; j += 256) {
        int w = binned[base + j];
        int p = atomicAdd(&cur2[(w >> 17) & 255], 1);
        csr[base + p] = w & 0x1FFFF;
    }
    __syncthreads();                          // csr slice complete (in-block, L2-hot)
    if (node < NN) {
        int beg = rp >> 8, deg = rp & 255;
        float ax = 0.f, ay = 0.f;
        int e = beg, end = beg + deg;
        for (; e + 4 <= end; e += 4) {
            int s0 = csr[e], s1 = csr[e + 1], s2 = csr[e + 2], s3 = csr[e + 3];
            float2 v0 = xs[s0], v1 = xs[s1], v2 = xs[s2], v3 = xs[s3];
            ax += (v0.x + v1.x) + (v2.x + v3.x);
            ay += (v0.y + v1.y) + (v2.y + v3.y);
        }
        for (; e < end; ++e) { float2 vv = xs[csr[e]]; ax += vv.x; ay += vv.y; }
        float di = dinv[node];
        float2 xn = xs[node];                 // self-loop term
        At[node] = make_float4(di * (ax + xn.x), di * (ay + xn.y), di, 0.f);
    }
}

// ---------------- layer-2 gather: R13-exact fly (late barrier, fixed-32 tail) ----------------
__global__ __launch_bounds__(256) void k_gather_fly(const float4* __restrict__ At,
        const int* __restrict__ rsp, const int* __restrict__ csr,
        const float* __restrict__ W1, const float* __restrict__ b1,
        const float* __restrict__ W2, const float* __restrict__ b2,
        const float* __restrict__ W3, float* __restrict__ h3) {
    __shared__ float WsT[32 * 36];            // transposed W2, row stride 36 (16B-aligned)
    __shared__ float accS[256];
    __shared__ float4 stage[8][32];
    int tid = threadIdx.x;
    for (int j = tid; j < 1024; j += 256) {
        int k = j >> 5, fo = j & 31;
        WsT[fo * 36 + k] = W2[j];             // WsT[f][k] = W2[k][f]
    }
    int g = tid >> 5, f = tid & 31;
    int node = blockIdx.x * 8 + g;                         // grid*8 == NN exactly
    float w0f = W1[f], w1f = W1[32 + f], bf = b1[f];
    float4 an = At[node];
    int r = rsp[node];
    float di = an.z;
    float vs = fmaf(an.y, w1f, fmaf(an.x, w0f, bf));
    float acc0 = di * fmaxf(vs, 0.f), acc1 = 0.f;          // self-loop
    int beg = r >> 8, deg = r & 255;
    float4* st = &stage[g][0];
    for (int b0 = 0; b0 < deg; b0 += 32) {
        float4 a = make_float4(0.f, 0.f, 0.f, 0.f);        // az=0 pads contribute 0
        if (b0 + f < deg) a = At[csr[beg + b0 + f]];
        st[f] = a;                                         // in-wave exchange,
        __asm__ __volatile__("" ::: "memory");             // DS pipe is in-order
#pragma unroll
        for (int j = 0; j < 32; j += 2) {
            float4 e0 = st[j], e1 = st[j + 1];             // same-addr broadcast reads
            float v0 = fmaf(e0.y, w1f, fmaf(e0.x, w0f, bf));
            acc0 = fmaf(e0.z, fmaxf(v0, 0.f), acc0);
            float v1 = fmaf(e1.y, w1f, fmaf(e1.x, w0f, bf));
            acc1 = fmaf(e1.z, fmaxf(v1, 0.f), acc1);
        }
        __asm__ __volatile__("" ::: "memory");
    }
    accS[tid] = di * (acc0 + acc1);           // agg2 = di * (sum + self)
    __syncthreads();                          // orders WsT staging vs reads (late barrier)
    int n0 = tid & 224;                       // group base
    float sum = b2[f];
    const float* wrow = &WsT[f * 36];
#pragma unroll
    for (int k = 0; k < 32; k += 4) {         // b128 reads: 16 DS reads total
        float4 a4 = *(const float4*)&accS[n0 + k];   // group-broadcast, aligned
        float4 w4 = *(const float4*)&wrow[k];        // lane-private row, aligned
        sum = fmaf(a4.x, w4.x, sum);
        sum = fmaf(a4.y, w4.y, sum);
        sum = fmaf(a4.z, w4.z, sum);
        sum = fmaf(a4.w, w4.w, sum);
    }
    float h2 = fmaxf(sum, 0.f);
    float v = di * h2 * W3[f];
#pragma unroll
    for (int off = 16; off > 0; off >>= 1) v += __shfl_down(v, off, 32);
    if (f == 0) h3[node] = v;
}

// ---------------- width-1 gather -> out ----------------
__global__ __launch_bounds__(256) void k_gather_out(const float* __restrict__ hs,
        const int* __restrict__ rsp, const int* __restrict__ csr,
        const float* __restrict__ dinv, const float* __restrict__ bias,
        float* __restrict__ out) {
    int node = blockIdx.x * 256 + threadIdx.x;
    if (node >= NN) return;
    int r = rsp[node];
    int beg = r >> 8, end = beg + (r & 255);
    float acc = hs[node];
    int e = beg;
    for (; e + 4 <= end; e += 4) {
        int s0 = csr[e], s1 = csr[e + 1], s2 = csr[e + 2], s3 = csr[e + 3];
        acc += (hs[s0] + hs[s1]) + (hs[s2] + hs[s3]);
    }
    for (; e < end; ++e) acc += hs[csr[e]];
    out[node] = dinv[node] * acc + bias[0];
}

extern "C" void kernel_launch(void* const* d_in, const int* in_sizes, int n_in,
                              void* d_out, int out_size, void* d_ws, size_t ws_size,
                              hipStream_t stream) {
    const float* x  = (const float*)d_in[0];
    const int*   ei = (const int*)d_in[1];   // [2, NE] int32
    const float* W1 = (const float*)d_in[2];
    const float* b1 = (const float*)d_in[3];
    const float* W2 = (const float*)d_in[4];
    const float* b2 = (const float*)d_in[5];
    const float* W3 = (const float*)d_in[6];
    const float* b3 = (const float*)d_in[7];
    float* out = (float*)d_out;

    char* w = (char*)d_ws;
    float4* At    = (float4*)w; w += NN * 16;           // 16B-aligned first, 1.6 MB
    float2* xs    = (float2*)w; w += NN * 8;
    int*   bh     = (int*)w;    w += NBLK2 * NB * 4;    // 0.9 MB block-hist/offsets
    int*   tot    = (int*)w;    w += NB * 4;
    int*   rsp    = (int*)w;    w += NN * 4;
    float* dinv   = (float*)w;  w += NN * 4;
    int*   binned = (int*)w;    w += NB * CAP * 4;      // 10.8 MB
    int*   csr    = (int*)w;    w += NB * CAP * 4;      // 10.8 MB
    float* h3     = (float*)w;  w += NN * 4;

    const int G_N = (NN + 255) / 256;        // 391
    const int G_G = NN / 8;                  // 12500 (exact)

    k_hist<<<NBLK2, 512, 0, stream>>>(ei, bh);
    k_offscan<<<NB, 256, 0, stream>>>(bh, tot);
    k_scatter2<<<NBLK2, 512, 0, stream>>>(ei, bh, binned);
    k_csr_count<<<NB, 256, 0, stream>>>(binned, tot, x, rsp, dinv, xs);
    k_csr_place<<<NB, 256, 0, stream>>>(binned, tot, rsp, xs, dinv, csr, At);
    k_gather_fly<<<G_G, 256, 0, stream>>>(At, rsp, csr, W1, b1, W2, b2, W3, h3);
    k_gather_out<<<G_N, 256, 0, stream>>>(h3, rsp, csr, dinv, b3, out);
}